// Round 12
// baseline (412.364 us; speedup 1.0000x reference)
//
#include <hip/hip_runtime.h>
#include <hip/hip_bf16.h>
#include <math.h>

// Problem constants
#define R_   8192    // B*S rows
#define DM   1024    // d_model
#define DFF  4096    // d_ff
#define NP   64      // n_patterns
#define KN   8       // K neurons

typedef __bf16 bf16x8 __attribute__((ext_vector_type(8)));
typedef float  f32x4  __attribute__((ext_vector_type(4)));

__device__ __forceinline__ unsigned short f2bf(float f) {
  union { float f; unsigned u; } v; v.f = f;
  unsigned u = v.u;
  return (unsigned short)((u + 0x7FFFu + ((u >> 16) & 1u)) >> 16);
}

__device__ __forceinline__ float dot4(const float4 a, const float4 b) {
  return a.x * b.x + a.y * b.y + a.z * b.z + a.w * b.w;
}

__device__ __forceinline__ void fma4(float4& a, float w, const float4 s) {
  a.x += w * s.x; a.y += w * s.y; a.z += w * s.z; a.w += w * s.w;
}

// ---------------------------------------------------------------- f32 -> bf16
__global__ __launch_bounds__(256) void cvt_bf16_kernel(
    const float* __restrict__ in, unsigned short* __restrict__ out, int n8) {
  int i = blockIdx.x * 256 + threadIdx.x;
  if (i >= n8) return;
  const float4* p = (const float4*)in + (size_t)i * 2;
  float4 a = p[0], b = p[1];
  uint4 r;
  r.x = (unsigned)f2bf(a.x) | ((unsigned)f2bf(a.y) << 16);
  r.y = (unsigned)f2bf(a.z) | ((unsigned)f2bf(a.w) << 16);
  r.z = (unsigned)f2bf(b.x) | ((unsigned)f2bf(b.y) << 16);
  r.w = (unsigned)f2bf(b.z) | ((unsigned)f2bf(b.w) << 16);
  ((uint4*)out)[i] = r;
}

// -------------------------------------------------------------- v materialize
__global__ __launch_bounds__(256) void vcomp_kernel(
    const float* __restrict__ sn,    // [R_][8][1024]
    const float* __restrict__ tw,    // [R_][8]
    float* __restrict__ v)           // [R_][1024]
{
  const int r = blockIdx.x;
  const int t = threadIdx.x;
  float w[KN];
#pragma unroll
  for (int k = 0; k < KN; ++k) w[k] = tw[(size_t)r * KN + k];
  const float* base = sn + (size_t)r * (KN * DM) + t * 4;
  float4 a = {0.f, 0.f, 0.f, 0.f};
#pragma unroll
  for (int k = 0; k < KN; ++k) fma4(a, w[k], *(const float4*)(base + k * DM));
  *(float4*)(v + (size_t)r * DM + t * 4) = a;
}

// ------------------------------------------------- pattern scores/topk/softmax
__global__ __launch_bounds__(256, 2) void score_kernel(
    const float* __restrict__ v,     // [R_][1024]
    const float* __restrict__ pq,    // [64][1024]
    int*   __restrict__ out_idx,     // [R_][4]
    float* __restrict__ out_w)       // [R_][4]
{
  const int lane = threadIdx.x & 63;
  const int wave = threadIdx.x >> 6;
  const int pos0 = (blockIdx.x * 4 + wave) * 4;

  float4 vr[4][4];
#pragma unroll
  for (int p = 0; p < 4; ++p) {
    const float4* s = (const float4*)(v + (size_t)(pos0 + p) * DM + lane * 16);
    vr[p][0] = s[0]; vr[p][1] = s[1]; vr[p][2] = s[2]; vr[p][3] = s[3];
  }

  float sreg[4];
#pragma unroll 1
  for (int pat = 0; pat < NP; ++pat) {
    const float4* q = (const float4*)(pq + pat * DM + lane * 16);
    const float4 q0 = q[0], q1 = q[1], q2 = q[2], q3 = q[3];
    float part[4];
#pragma unroll
    for (int p = 0; p < 4; ++p)
      part[p] = dot4(q0, vr[p][0]) + dot4(q1, vr[p][1]) +
                dot4(q2, vr[p][2]) + dot4(q3, vr[p][3]);
#pragma unroll
    for (int off = 32; off >= 1; off >>= 1) {
#pragma unroll
      for (int p = 0; p < 4; ++p)
        part[p] += __shfl_xor(part[p], off, 64);
    }
    if (lane == pat) {
#pragma unroll
      for (int p = 0; p < 4; ++p) sreg[p] = part[p] * 0.03125f; // /sqrt(1024)
    }
  }

#pragma unroll
  for (int p = 0; p < 4; ++p) {
    float cur = sreg[p];
    float m0, m1, m2, m3; int i0, i1, i2, i3;
#define ARGMAX_STEP(MV, MI)                                   \
    {                                                         \
      float bv = cur; int bi = lane;                          \
      _Pragma("unroll")                                       \
      for (int off = 32; off >= 1; off >>= 1) {               \
        float ov = __shfl_xor(bv, off, 64);                   \
        int   oi = __shfl_xor(bi, off, 64);                   \
        if (ov > bv || (ov == bv && oi < bi)) { bv = ov; bi = oi; } \
      }                                                       \
      MV = bv; MI = bi;                                       \
      if (lane == bi) cur = -3.0e38f;                         \
    }
    ARGMAX_STEP(m0, i0) ARGMAX_STEP(m1, i1) ARGMAX_STEP(m2, i2) ARGMAX_STEP(m3, i3)
#undef ARGMAX_STEP
    const float e1 = __expf(m1 - m0), e2 = __expf(m2 - m0), e3 = __expf(m3 - m0);
    const float inv = 1.f / (1.f + e1 + e2 + e3);
    if (lane < 4) {
      const int r = pos0 + p;
      const int myi = (lane == 0) ? i0 : (lane == 1) ? i1 : (lane == 2) ? i2 : i3;
      const float mye = (lane == 0) ? 1.f : (lane == 1) ? e1 : (lane == 2) ? e2 : e3;
      out_idx[r * 4 + lane] = myi;
      out_w[r * 4 + lane] = mye * inv;
    }
  }
}

// ---------------------------------------------------------------- bf16 GEMM
__device__ __forceinline__ void gll16(const void* g, void* l) {
  __builtin_amdgcn_global_load_lds(
      (const __attribute__((address_space(1))) unsigned int*)g,
      (__attribute__((address_space(3))) unsigned int*)l, 16, 0, 0);
}

// m97-replica GEMM (the R2-proven kernel, TLP-maximized):
// 128x128 tile, 4 waves (2x2), wave-tile 64x64, BK=32, SINGLE 16KB LDS
// buffer, plain __syncthreads (compiler emits verified fine-grained
// lgkmcnt interleave), NO launch-bounds cap -> VGPR-limited 3-4 blocks/CU:
// wave-level TLP fills the barrier-drain stall (m114), which ILP variants
// (R3-R8, all ~19% MfmaUtil at <=2 blocks/CU) could not.
// L2-aware XCD mapping (R11, FETCH 107->77MB): per-XCD {B-group + A-panel}
// fits 4MB L2.
template <int K, int N, int MODE>
__global__ __launch_bounds__(256) void gemm_kernel(
    const unsigned short* __restrict__ A,
    const unsigned short* __restrict__ Bm,
    const float* __restrict__ bias,
    const int*   __restrict__ pidx,
    const float* __restrict__ pwt,
    const float* __restrict__ gates,  // [64][DFF]
    void* __restrict__ Cout)
{
  __shared__ __align__(16) unsigned short As[128 * 32];
  __shared__ __align__(16) unsigned short Bs[128 * 32];
  const int tid  = threadIdx.x;
  const int lane = tid & 63;
  const int wid  = tid >> 6;
  const int wr   = wid >> 1;
  const int wc   = wid & 1;

  // L2-aware bijective mapping: XCD = bid&7 owns a fixed bcol group;
  // bcol-minor inner order so consecutive blocks share the A-panel.
  const int xcd = (int)blockIdx.x & 7, lid = (int)blockIdx.x >> 3;
  int brow, bcol;
  if (MODE == 0) { brow = lid >> 2; bcol = xcd * 4 + (lid & 3); } // 64 x 32
  else           { brow = lid;      bcol = xcd;                 } // 64 x 8

  const unsigned short* Ab = A  + (size_t)brow * 128 * K;
  const unsigned short* Bb = Bm + (size_t)bcol * 128 * K;

  f32x4 acc[4][4];
#pragma unroll
  for (int m = 0; m < 4; ++m)
#pragma unroll
    for (int n = 0; n < 4; ++n)
      acc[m][n] = (f32x4){0.f, 0.f, 0.f, 0.f};

  const int srow = tid >> 2;            // staging row 0..63 (+64 for 2nd call)
  const int scol = (tid & 3) * 8;       // staging col (8 bf16 = 16B)
  char* ldsA = (char*)As + (tid >> 6) * 1024;  // wave-uniform base
  char* ldsB = (char*)Bs + (tid >> 6) * 1024;

  const int arow = wr * 64 + (lane & 15);
  const int bro  = wc * 64 + (lane & 15);
  const int koff = (lane >> 4) * 8;

#pragma unroll 1
  for (int k0 = 0; k0 < K; k0 += 32) {
    if (k0) __syncthreads();            // frag reads done before overwrite
    gll16(Ab + (size_t)srow * K + k0 + scol,        ldsA);
    gll16(Ab + (size_t)(srow + 64) * K + k0 + scol, ldsA + 4096);
    gll16(Bb + (size_t)srow * K + k0 + scol,        ldsB);
    gll16(Bb + (size_t)(srow + 64) * K + k0 + scol, ldsB + 4096);
    __syncthreads();                    // vmcnt(0) drain -> staged data visible

    bf16x8 af[4], bfr[4];
#pragma unroll
    for (int m = 0; m < 4; ++m)
      af[m] = *(const bf16x8*)(As + (arow + m * 16) * 32 + koff);
#pragma unroll
    for (int n = 0; n < 4; ++n)
      bfr[n] = *(const bf16x8*)(Bs + (bro + n * 16) * 32 + koff);
#pragma unroll
    for (int m = 0; m < 4; ++m)
#pragma unroll
      for (int n = 0; n < 4; ++n)
        acc[m][n] = __builtin_amdgcn_mfma_f32_16x16x32_bf16(
            af[m], bfr[n], acc[m][n], 0, 0, 0);
  }

  // Epilogue. C/D layout: col = lane&15, row = (lane>>4)*4 + reg.
  const int crow0 = brow * 128 + wr * 64;
  const int ccol0 = bcol * 128 + wc * 64 + (lane & 15);
  const int rsub  = (lane >> 4) * 4;

  if (MODE == 0) {
    unsigned short* H = (unsigned short*)Cout;
#pragma unroll
    for (int m = 0; m < 4; ++m) {
      const int rbase = crow0 + m * 16 + rsub;
      int   ia[4][4];
      float wa[4][4];
#pragma unroll
      for (int j = 0; j < 4; ++j) {
        const int4   iq = *(const int4*)(pidx + (size_t)(rbase + j) * 4);
        const float4 wq = *(const float4*)(pwt + (size_t)(rbase + j) * 4);
        ia[j][0] = iq.x; ia[j][1] = iq.y; ia[j][2] = iq.z; ia[j][3] = iq.w;
        wa[j][0] = wq.x; wa[j][1] = wq.y; wa[j][2] = wq.z; wa[j][3] = wq.w;
      }
#pragma unroll
      for (int n = 0; n < 4; ++n) {
        const int col = ccol0 + n * 16;
        const float ub = bias[col];
#pragma unroll
        for (int j = 0; j < 4; ++j) {
          float g = wa[j][0] * gates[(size_t)ia[j][0] * DFF + col]
                  + wa[j][1] * gates[(size_t)ia[j][1] * DFF + col]
                  + wa[j][2] * gates[(size_t)ia[j][2] * DFF + col]
                  + wa[j][3] * gates[(size_t)ia[j][3] * DFF + col];
          const float u   = acc[m][n][j] + ub;
          const float val = u * (1.f / (1.f + __expf(-g)));
          const float h   = 0.5f * val * (1.f + erff(val * 0.70710678118654752f));
          H[(size_t)(rbase + j) * N + col] = f2bf(h);
        }
      }
    }
  } else {
    float* O = (float*)Cout;
#pragma unroll
    for (int m = 0; m < 4; ++m) {
      const int rbase = crow0 + m * 16 + rsub;
#pragma unroll
      for (int n = 0; n < 4; ++n) {
        const int col = ccol0 + n * 16;
        const float db = bias[col];
#pragma unroll
        for (int j = 0; j < 4; ++j)
          O[(size_t)(rbase + j) * N + col] = acc[m][n][j] + db;
      }
    }
  }
}

// ---------------------------------------------------------------------- launch
extern "C" void kernel_launch(void* const* d_in, const int* in_sizes, int n_in,
                              void* d_out, int out_size, void* d_ws, size_t ws_size,
                              hipStream_t stream) {
  const float* x     = (const float*)d_in[0];
  const float* tw    = (const float*)d_in[3];
  const float* sn    = (const float*)d_in[4];
  const float* pq    = (const float*)d_in[5];
  const float* gates = (const float*)d_in[6];
  const float* upw   = (const float*)d_in[7];
  const float* upb   = (const float*)d_in[8];
  const float* dnw   = (const float*)d_in[9];
  const float* dnb   = (const float*)d_in[10];
  float* out = (float*)d_out;

  char* p = (char*)d_ws;
  unsigned short* xb  = (unsigned short*)p; p += (size_t)R_ * DM * 2;
  unsigned short* uwb = (unsigned short*)p; p += (size_t)DFF * DM * 2;
  unsigned short* dwb = (unsigned short*)p; p += (size_t)DM * DFF * 2;
  unsigned short* H   = (unsigned short*)p; p += (size_t)R_ * DFF * 2;
  int*   pidx = (int*)p;   p += (size_t)R_ * 4 * sizeof(int);
  float* pwt  = (float*)p; p += (size_t)R_ * 4 * sizeof(float);
  float* vbuf = (float*)p; p += (size_t)R_ * DM * sizeof(float);

  cvt_bf16_kernel<<<(R_ * DM / 8) / 256, 256, 0, stream>>>(x, xb, R_ * DM / 8);
  cvt_bf16_kernel<<<(DFF * DM / 8) / 256, 256, 0, stream>>>(upw, uwb, DFF * DM / 8);
  cvt_bf16_kernel<<<(DM * DFF / 8) / 256, 256, 0, stream>>>(dnw, dwb, DM * DFF / 8);

  vcomp_kernel<<<R_, 256, 0, stream>>>(sn, tw, vbuf);
  score_kernel<<<R_ / 16, 256, 0, stream>>>(vbuf, pq, pidx, pwt);

  // gemm1: 2048 blocks (8 XCD x 64 brow x 4 bcol); gemm2: 512 blocks
  gemm_kernel<DM, DFF, 0><<<(R_ / 128) * (DFF / 128), 256, 0, stream>>>(
      xb, uwb, upb, pidx, pwt, gates, (void*)H);
  gemm_kernel<DFF, DM, 1><<<(R_ / 128) * (DM / 128), 256, 0, stream>>>(
      H, dwb, dnb, nullptr, nullptr, nullptr, (void*)out);
}